// Round 9
// baseline (254.891 us; speedup 1.0000x reference)
//
#include <hip/hip_runtime.h>
#include <stdint.h>

// CIN forward, MI355X. R9: 32x32x16 f16 MFMA (layouts R5-verified), waves =
// batch(2) x o-half(2) x d-half(2): one B-frag build (1 perm + 8 pkmul)
// feeds 4 MFMAs (2 ot x 2 kh) -> 4.4x less build-VALU per FLOP than R8
// (R8's immovable VALUBusy 56% ~= builds at quarter-rate pk ops).
// R8-proven parts kept: scalar rolling W offset + imm, depth-2 slot
// rotation, consume-then-reload, sched_barrier(0). d-halves combine via
// double-buffered sOut. 512 thr, 2 batches/block, grid 512.

typedef __attribute__((ext_vector_type(8))) _Float16 f16x8;
typedef __attribute__((ext_vector_type(2))) _Float16 f16x2;
typedef __attribute__((ext_vector_type(16))) float f32x16;
typedef __attribute__((ext_vector_type(4))) float f32x4;
typedef __attribute__((ext_vector_type(4))) int i32x4;

static __device__ __forceinline__ uint32_t pkmul(uint32_t a, uint32_t b) {
  f16x2 r = __builtin_bit_cast(f16x2, a) * __builtin_bit_cast(f16x2, b);
  return __builtin_bit_cast(uint32_t, r);  // v_pk_mul_f16
}
static __device__ __forceinline__ uint32_t pkcvt(float a, float b) {
  return __builtin_bit_cast(uint32_t, __builtin_amdgcn_cvt_pkrtz(a, b));
}
static __device__ __forceinline__ f16x8 asf16(i32x4 v) {
  return __builtin_bit_cast(f16x8, v);
}

#define HP 136  // hT row: 128 ch + 8 pad (tail hv prefetch lands in pad)

__global__ __launch_bounds__(512, 4) void cin_main(
    const float* __restrict__ x, const uint16_t* __restrict__ wp,
    const float* __restrict__ bias0, const float* __restrict__ bias1,
    const float* __restrict__ bias2, float* __restrict__ out) {
  __shared__ __align__(16) uint16_t hT[2][64][HP];  // [batch][d][chan] fp16
  __shared__ float sOut[2][2][2][128];              // [L&1][batch][dhalf][o]

  const int tid = threadIdx.x;
  const int w = tid >> 6, lane = tid & 63;
  const int p  = __builtin_amdgcn_readfirstlane(w >> 2);       // batch
  const int oh = __builtin_amdgcn_readfirstlane((w >> 1) & 1); // o-half: ot {2oh,2oh+1}
  const int th = __builtin_amdgcn_readfirstlane(w & 1);        // d-half
  const int l5 = lane >> 5, l31 = lane & 31;
  const int dd = th * 32 + l31;  // this lane's d (B n-col / C col)
  const int bb = blockIdx.x * 2;

  // ---- stage x -> hT[p][d][m] fp16 (layer-0 h == x; 32 channels)
  for (int e = tid; e < 4096; e += 512) {
    int p2 = e >> 11, m = (e >> 6) & 31, d = e & 63;
    hT[p2][d][m] =
        __builtin_bit_cast(uint16_t, (_Float16)x[(size_t)(bb + p2) * 2048 + m * 64 + d]);
  }
  __syncthreads();

  // ---- x B-frags (loop-invariant): xf_kh[j] = x[m = kh*16 + l5*8 + j][dd]
  i32x4 xf0 = *(const i32x4*)&hT[p][dd][0 * 16 + l5 * 8];  // ds_read_b128
  i32x4 xf1 = *(const i32x4*)&hT[p][dd][1 * 16 + l5 * 8];

  f32x16 acc[2];  // [g]: ot = 2oh+g

#pragma unroll
  for (int L = 0; L < 3; ++L) {
    const int Kch = (L == 0) ? 32 : 128;
    const uint16_t* wl = (L == 0) ? wp : (L == 1) ? wp + 131072 : wp + 655360;
    const float* bias = (L == 0) ? bias0 : (L == 1) ? bias1 : bias2;

    // frag(ot,c,kh) at ((ot*Kch + c)*2 + kh)*512 elems (R5-verified pack)
    const uint16_t* wg0 = wl + (size_t)(2 * oh + 0) * Kch * 1024;
    const uint16_t* wg1 = wl + (size_t)(2 * oh + 1) * Kch * 1024;
    const int loff = lane * 8;

#pragma unroll
    for (int g = 0; g < 2; ++g)
#pragma unroll
      for (int r = 0; r < 16; ++r) acc[g][r] = 0.f;

    i32x4 slot0[4], slot1[4];  // [g*2+kh], 16 VGPR each, depth-2 rotation
    uint2 hvA, hvB;
    const uint16_t* hrow = &hT[p][dd][0];

    auto reload = [&](i32x4 (&sl)[4], int co) {
      sl[0] = *(const i32x4*)(wg0 + co + loff);
      sl[1] = *(const i32x4*)(wg0 + co + 512 + loff);
      sl[2] = *(const i32x4*)(wg1 + co + loff);
      sl[3] = *(const i32x4*)(wg1 + co + 512 + loff);
    };
    auto compCh = [&](const i32x4 (&sl)[4], uint32_t word, uint32_t selmask) {
      uint32_t hd = __builtin_amdgcn_perm(word, word, selmask);  // dup h[c,dd]
      i32x4 bf0, bf1;  // P[c*32 + kh*16 + k][dd] = h[c,dd]*x[k][dd]
#pragma unroll
      for (int k = 0; k < 4; ++k) {
        bf0[k] = (int)pkmul(hd, (uint32_t)xf0[k]);
        bf1[k] = (int)pkmul(hd, (uint32_t)xf1[k]);
      }
      // interleave the two acc chains to cover MFMA latency
      acc[0] = __builtin_amdgcn_mfma_f32_32x32x16_f16(asf16(sl[0]), asf16(bf0), acc[0], 0, 0, 0);
      acc[1] = __builtin_amdgcn_mfma_f32_32x32x16_f16(asf16(sl[2]), asf16(bf0), acc[1], 0, 0, 0);
      acc[0] = __builtin_amdgcn_mfma_f32_32x32x16_f16(asf16(sl[1]), asf16(bf1), acc[0], 0, 0, 0);
      acc[1] = __builtin_amdgcn_mfma_f32_32x32x16_f16(asf16(sl[3]), asf16(bf1), acc[1], 0, 0, 0);
    };

    // prologue: slots = ch0, ch1; co -> ch2; hvA = ch0..3
    reload(slot0, 0);
    reload(slot1, 1024);
    int co = 2048;
    const int comax = (Kch - 2) * 1024;
    hvA = *(const uint2*)hrow; hrow += 4;
    __builtin_amdgcn_sched_barrier(0);

    // half-body: 4 channels from hvC; prefetch next 4 into hvN
    auto halfBody = [&](uint2& hvC, uint2& hvN) {
      hvN = *(const uint2*)hrow; hrow += 4;  // tail reads land in row pad
      compCh(slot0, hvC.x, 0x01000100u);  // ch c+0 (consume, THEN reload)
      reload(slot0, co);
      __builtin_amdgcn_sched_barrier(0);
      compCh(slot1, hvC.x, 0x03020302u);  // ch c+1
      reload(slot1, co + 1024);
      __builtin_amdgcn_sched_barrier(0);
      co = (co + 2048 < comax) ? co + 2048 : comax;  // scalar clamp
      compCh(slot0, hvC.y, 0x01000100u);  // ch c+2
      reload(slot0, co);
      __builtin_amdgcn_sched_barrier(0);
      compCh(slot1, hvC.y, 0x03020302u);  // ch c+3
      reload(slot1, co + 1024);
      __builtin_amdgcn_sched_barrier(0);
      co = (co + 2048 < comax) ? co + 2048 : comax;
    };

#pragma unroll 1
    for (int c0 = 0; c0 < Kch; c0 += 8) {
      halfBody(hvA, hvB);
      halfBody(hvB, hvA);
    }

    // ---- bias + ReLU. C layout (R5/m74-verified):
    // col d = l31 (+32*th), row o_local = (r&3) + 8*(r>>2) + 4*l5
#pragma unroll
    for (int g = 0; g < 2; ++g)
#pragma unroll
      for (int q4 = 0; q4 < 4; ++q4) {
        f32x4 bv = *(const f32x4*)(bias + (2 * oh + g) * 32 + 8 * q4 + 4 * l5);
#pragma unroll
        for (int rr = 0; rr < 4; ++rr)
          acc[g][q4 * 4 + rr] = fmaxf(acc[g][q4 * 4 + rr] + bv[rr], 0.f);
      }

    // ---- d-partials: butterfly over the 32 d-lanes of this half
#pragma unroll
    for (int g = 0; g < 2; ++g)
#pragma unroll
      for (int r = 0; r < 16; ++r) {
        float s = acc[g][r];
        s += __shfl_xor(s, 1);
        s += __shfl_xor(s, 2);
        s += __shfl_xor(s, 4);
        s += __shfl_xor(s, 8);
        s += __shfl_xor(s, 16);
        if (l31 == 0)
          sOut[L & 1][p][th][(2 * oh + g) * 32 + (r & 3) + 8 * (r >> 2) + 4 * l5] = s;
      }

    __syncthreads();  // sOut visible; all hT reads of this layer complete

    if (L < 2) {  // next-layer h -> hT rows [dd], disjoint per wave
#pragma unroll
      for (int g = 0; g < 2; ++g)
#pragma unroll
        for (int q4 = 0; q4 < 4; ++q4) {
          uint2 pk;
          pk.x = pkcvt(acc[g][q4 * 4 + 0], acc[g][q4 * 4 + 1]);
          pk.y = pkcvt(acc[g][q4 * 4 + 2], acc[g][q4 * 4 + 3]);
          *(uint2*)&hT[p][dd][(2 * oh + g) * 32 + 8 * q4 + 4 * l5] = pk;
        }
    }

    // combine d-halves -> out (coalesced; 256 lanes = 2 batches x 128 o)
    if (tid < 256) {
      int b2 = tid >> 7, o = tid & 127;
      out[(size_t)(bb + b2) * 384 + L * 128 + o] =
          sOut[L & 1][b2][0][o] + sOut[L & 1][b2][1][o];
    }

    if (L < 2) __syncthreads();  // hT writes visible before next K-loop
  }
}

// Pack W fp32 -> fp16 32x32x16 A-frags (R5-verified math, merged to one
// kernel): flat idx = ((ot*Kch + c)*2 + kh)*64 + lane, 8 elems/thread;
// content A[m=lane&31][k=(lane>>5)*8+j] = W[ot*32+m][c*32 + kh*16 + k].
__global__ void pack_w_all(const float* __restrict__ W0, const float* __restrict__ W1,
                           const float* __restrict__ W2, uint16_t* __restrict__ Wp) {
  int blk = blockIdx.x;
  const float* W;
  uint16_t* dst;
  int kshift;
  if (blk < 64)       { W = W0; dst = Wp;          kshift = 5; }
  else if (blk < 320) { W = W1; dst = Wp + 131072; kshift = 7; blk -= 64; }
  else                { W = W2; dst = Wp + 655360; kshift = 7; blk -= 320; }
  const int Kch = 1 << kshift;
  int idx = blk * 256 + threadIdx.x;
  int lane = idx & 63;
  int kh = (idx >> 6) & 1;
  int c = (idx >> 7) & (Kch - 1);
  int ot = idx >> (7 + kshift);
  const float* src = W + (size_t)(ot * 32 + (lane & 31)) * (Kch * 32) +
                     c * 32 + kh * 16 + (lane >> 5) * 8;
  uint4 val;
  val.x = pkcvt(src[0], src[1]);
  val.y = pkcvt(src[2], src[3]);
  val.z = pkcvt(src[4], src[5]);
  val.w = pkcvt(src[6], src[7]);
  *(uint4*)(dst + (size_t)idx * 8) = val;
}

extern "C" void kernel_launch(void* const* d_in, const int* in_sizes, int n_in,
                              void* d_out, int out_size, void* d_ws, size_t ws_size,
                              hipStream_t stream) {
  (void)in_sizes; (void)n_in; (void)out_size; (void)ws_size;
  const float* x  = (const float*)d_in[0];
  const float* W0 = (const float*)d_in[1];
  const float* b0 = (const float*)d_in[2];
  const float* W1 = (const float*)d_in[3];
  const float* b1 = (const float*)d_in[4];
  const float* W2 = (const float*)d_in[5];
  const float* b2 = (const float*)d_in[6];
  uint16_t* wpacked = (uint16_t*)d_ws;  // 2.25 MB of ws

  hipLaunchKernelGGL(pack_w_all, dim3(576), dim3(256), 0, stream, W0, W1, W2, wpacked);
  hipLaunchKernelGGL(cin_main, dim3(512), dim3(512), 0, stream,
                     x, wpacked, b0, b1, b2, (float*)d_out);
}